// Round 1
// baseline (145.683 us; speedup 1.0000x reference)
//
#include <hip/hip_runtime.h>

#define NB 32
#define RR 128
#define FF 128
#define FT 32   // f-tile width
#define SB 132  // LDS stride for transposed b-tile: 132*4B = 528B, 16B-aligned rows

// v2: software-pipelined staging.
// - Tile t+1's x2 loads are issued into REGISTERS at the start of tile t's
//   compute (T14 async-stage split). v1 issued them between two back-to-back
//   barriers, exposing full L2/HBM latency 4x per block -- worst right after
//   the harness's 268 MB ws-poison fill, whose L3 writeback drains during our
//   kernel and inflates load latency.
// - sh_b double-buffered -> ONE __syncthreads per tile (was 2). Write to
//   buf^1 is safe: last readers of buf^1 were tile t-1, fenced by its barrier.
// - a-row tile hoisted to 8 float4 regs per tile via broadcast ds_read_b128
//   (no per-f scalar LDS reads in the inner loop). Static indexing only.
// - Still no d_ws use: keeps the 268 MB poison fill as the only HBM consumer.
__global__ __launch_bounds__(256) void gauss_fused(const float* __restrict__ x1,
                                                   const float* __restrict__ x2,
                                                   const float* __restrict__ sigma,
                                                   const float* __restrict__ mean,
                                                   float* __restrict__ out) {
  __shared__ __align__(16) float sh_b[2][FT * SB];  // 2 x 16.5 KB, transposed [f][j]
  __shared__ __align__(16) float sh_a[8 * FF];      // 4 KB, 8 x1 rows, mean folded

  const int bid = blockIdx.x;
  const int n = bid >> 4;          // 16 i-octets per n
  const int i0 = (bid & 15) << 3;  // 8 rows per block
  const int tid = threadIdx.x;
  const int tx = tid & 31;   // j-quad
  const int ty = tid >> 5;   // row 0..7

  const float mval = mean[0];
  const float sg = sigma[0];
  const float cneg = -1.0f / (2.0f * sg * sg);

  const float* __restrict__ x2base = x2 + (size_t)n * RR * FF;
  const int jj = tid >> 3;        // 0..31: row within 32-row staging chunk
  const int fo = (tid & 7) << 2;  // 0,4,...,28: f-offset quad within tile

  // ---- prologue: issue tile-0 loads + stage sh_a, then write tile 0 ----
  float4 p0 = *(const float4*)(x2base + (size_t)(jj + 0) * FF + fo);
  float4 p1 = *(const float4*)(x2base + (size_t)(jj + 32) * FF + fo);
  float4 p2 = *(const float4*)(x2base + (size_t)(jj + 64) * FF + fo);
  float4 p3 = *(const float4*)(x2base + (size_t)(jj + 96) * FF + fo);
  {
    const float4 v = ((const float4*)(x1 + (size_t)(n * RR + i0) * FF))[tid];
    ((float4*)sh_a)[tid] = make_float4(v.x - mval, v.y - mval, v.z - mval, v.w - mval);
  }
  {
    float* dst = sh_b[0];
    dst[(fo + 0) * SB + (jj + 0)] = p0.x;
    dst[(fo + 1) * SB + (jj + 0)] = p0.y;
    dst[(fo + 2) * SB + (jj + 0)] = p0.z;
    dst[(fo + 3) * SB + (jj + 0)] = p0.w;
    dst[(fo + 0) * SB + (jj + 32)] = p1.x;
    dst[(fo + 1) * SB + (jj + 32)] = p1.y;
    dst[(fo + 2) * SB + (jj + 32)] = p1.z;
    dst[(fo + 3) * SB + (jj + 32)] = p1.w;
    dst[(fo + 0) * SB + (jj + 64)] = p2.x;
    dst[(fo + 1) * SB + (jj + 64)] = p2.y;
    dst[(fo + 2) * SB + (jj + 64)] = p2.z;
    dst[(fo + 3) * SB + (jj + 64)] = p2.w;
    dst[(fo + 0) * SB + (jj + 96)] = p3.x;
    dst[(fo + 1) * SB + (jj + 96)] = p3.y;
    dst[(fo + 2) * SB + (jj + 96)] = p3.z;
    dst[(fo + 3) * SB + (jj + 96)] = p3.w;
  }
  __syncthreads();

  float acc0 = 0.f, acc1 = 0.f, acc2 = 0.f, acc3 = 0.f;
  const int j0 = tx << 2;
  int buf = 0;

#pragma unroll
  for (int t = 0; t < FF / FT; ++t) {
    // Issue next tile's global loads FIRST: in flight under this tile's FMAs.
    float4 q[4];
    if (t < 3) {
      const float* src = x2base + (size_t)(t + 1) * FT + fo;
#pragma unroll
      for (int p = 0; p < 4; ++p)
        q[p] = *(const float4*)(src + (size_t)(jj + 32 * p) * FF);
    }

    // a-tile -> 8 float4 regs (broadcast LDS reads, 2 addrs per wave)
    float4 a4[8];
    {
      const float4* asrc = (const float4*)(sh_a + ty * FF + t * FT);
#pragma unroll
      for (int fq = 0; fq < 8; ++fq) a4[fq] = asrc[fq];
    }

    const float* __restrict__ bb = sh_b[buf];
#pragma unroll
    for (int fq = 0; fq < 8; ++fq) {
      const float4 av = a4[fq];
#pragma unroll
      for (int k = 0; k < 4; ++k) {
        const float a = (k == 0) ? av.x : (k == 1) ? av.y : (k == 2) ? av.z : av.w;
        const float4 b = *(const float4*)(bb + (fq * 4 + k) * SB + j0);  // lane-consecutive b128
        float d;
        d = a - b.x; acc0 = fmaf(d, d, acc0);
        d = a - b.y; acc1 = fmaf(d, d, acc1);
        d = a - b.z; acc2 = fmaf(d, d, acc2);
        d = a - b.w; acc3 = fmaf(d, d, acc3);
      }
    }

    // Drain prefetch into the other buffer; single barrier per tile.
    if (t < 3) {
      float* dst = sh_b[buf ^ 1];
#pragma unroll
      for (int p = 0; p < 4; ++p) {
        dst[(fo + 0) * SB + (jj + 32 * p)] = q[p].x;
        dst[(fo + 1) * SB + (jj + 32 * p)] = q[p].y;
        dst[(fo + 2) * SB + (jj + 32 * p)] = q[p].z;
        dst[(fo + 3) * SB + (jj + 32 * p)] = q[p].w;
      }
      __syncthreads();
      buf ^= 1;
    }
  }

  // kernel_value = exp(-ds / (2 sigma^2)), then softmax over j (row = 32
  // lanes x 4 regs; xor offsets <32 stay within each 32-lane half-wave).
  const float k0 = __expf(acc0 * cneg);
  const float k1 = __expf(acc1 * cneg);
  const float k2 = __expf(acc2 * cneg);
  const float k3 = __expf(acc3 * cneg);

  float mx = fmaxf(fmaxf(k0, k1), fmaxf(k2, k3));
#pragma unroll
  for (int off = 16; off >= 1; off >>= 1) mx = fmaxf(mx, __shfl_xor(mx, off, 64));
  const float e0 = __expf(k0 - mx);
  const float e1 = __expf(k1 - mx);
  const float e2 = __expf(k2 - mx);
  const float e3 = __expf(k3 - mx);
  float ssum = e0 + e1 + e2 + e3;
#pragma unroll
  for (int off = 16; off >= 1; off >>= 1) ssum += __shfl_xor(ssum, off, 64);
  const float r = 1.0f / ssum;

  *(float4*)(out + (size_t)(n * RR + i0 + ty) * RR + j0) =
      make_float4(e0 * r, e1 * r, e2 * r, e3 * r);
}

extern "C" void kernel_launch(void* const* d_in, const int* in_sizes, int n_in,
                              void* d_out, int out_size, void* d_ws, size_t ws_size,
                              hipStream_t stream) {
  const float* x1 = (const float*)d_in[0];
  const float* x2 = (const float*)d_in[1];
  const float* sigma = (const float*)d_in[2];
  const float* mean = (const float*)d_in[3];
  float* out = (float*)d_out;
  (void)d_ws; (void)ws_size;  // deliberately unused: keep the 268 MB ws poison off our path

  gauss_fused<<<dim3(NB * 16), dim3(256), 0, stream>>>(x1, x2, sigma, mean, out);
}

// Round 2
// 68.620 us; speedup vs baseline: 2.1230x; 2.1230x over previous
//
#include <hip/hip_runtime.h>

#define NB 32
#define RR 128
#define FF 128
#define SB 132  // LDS row stride for transposed b: 132*4B = 528B, 16B-aligned rows,
                // 4-way write conflict (~1.58x) on staging, conflict-free b128 reads

// v3: whole-slice LDS staging, ONE barrier, 2 rows/thread.
// v2 post-mortem: full t-unroll + prefetch regs + a4 hoist -> 256 VGPR + scratch
// spills (WRITE_SIZE 148 MB, FETCH 82.5 MB) -> 90 us kernel. Pipelining removed.
// Instead: x2[n] slice is only 64 KB -> stage it ALL in LDS (67.6 KB padded,
// gfx950 static LDS up to 160 KB/CU; 128 KB HW-verified), so the kernel has a
// single __syncthreads and zero steady-state staging latency to hide.
// 16 i-rows per block (rows ty and ty+8 per thread): each b128 LDS read feeds
// 16 FMAs (was 8), halving per-CU LDS read traffic -> ~3.8 us LDS-pipe floor.
// Grid 256 blocks = 1 block/CU; occupancy is grid-bound, so modest VGPR use is
// harmless, but NO big live arrays -> no spills.
// Still no d_ws use: the 268 MB harness poison fill stays the only big HBM user.
__global__ __launch_bounds__(256) void gauss_fused(const float* __restrict__ x1,
                                                   const float* __restrict__ x2,
                                                   const float* __restrict__ sigma,
                                                   const float* __restrict__ mean,
                                                   float* __restrict__ out) {
  __shared__ __align__(16) float sh_b[FF * SB];   // 67584 B, transposed [f][j]
  __shared__ __align__(16) float sh_a[16 * FF];   // 8192 B, 16 x1 rows, mean folded

  const int bid = blockIdx.x;
  const int n = bid >> 3;          // 8 row-blocks per n
  const int i0 = (bid & 7) << 4;   // 16 rows per block
  const int tid = threadIdx.x;
  const int tx = tid & 31;   // j-quad
  const int ty = tid >> 5;   // 0..7 -> rows i0+ty and i0+ty+8

  const float mval = mean[0];
  const float sg = sigma[0];
  const float cneg = -1.0f / (2.0f * sg * sg);

  const float* __restrict__ x2base = x2 + (size_t)n * RR * FF;

  // Stage 16 x1 rows (2048 floats) with mean pre-folded: two float4/thread.
  {
    const float4* asrc = (const float4*)(x1 + (size_t)(n * RR + i0) * FF);
    const float4 v0 = asrc[tid];
    const float4 v1 = asrc[tid + 256];
    ((float4*)sh_a)[tid] = make_float4(v0.x - mval, v0.y - mval, v0.z - mval, v0.w - mval);
    ((float4*)sh_a)[tid + 256] = make_float4(v1.x - mval, v1.y - mval, v1.z - mval, v1.w - mval);
  }

  // Stage the FULL 128x128 x2 slice transposed: 16 coalesced float4 loads and
  // 64 scalar LDS writes per thread (4-way bank conflict on writes, one-time).
  const int jj = tid >> 3;        // 0..31: j within each 32-row chunk
  const int fo = (tid & 7) << 2;  // 0,4,...,28: f-quad within each 32-f chunk
#pragma unroll
  for (int fc = 0; fc < 4; ++fc) {
    const int f0 = (fc << 5) + fo;
#pragma unroll
    for (int p = 0; p < 4; ++p) {
      const int j = jj + (p << 5);
      const float4 v = *(const float4*)(x2base + (size_t)j * FF + f0);
      sh_b[(f0 + 0) * SB + j] = v.x;
      sh_b[(f0 + 1) * SB + j] = v.y;
      sh_b[(f0 + 2) * SB + j] = v.z;
      sh_b[(f0 + 3) * SB + j] = v.w;
    }
  }
  __syncthreads();  // the ONLY barrier

  float acc00 = 0.f, acc01 = 0.f, acc02 = 0.f, acc03 = 0.f;
  float acc10 = 0.f, acc11 = 0.f, acc12 = 0.f, acc13 = 0.f;
  const int j0 = tx << 2;
  const float* __restrict__ arow0 = sh_a + ty * FF;
  const float* __restrict__ arow1 = sh_a + (ty + 8) * FF;

#pragma unroll 4
  for (int fq = 0; fq < 32; ++fq) {
    const float4 a0 = *(const float4*)(arow0 + (fq << 2));  // broadcast b128
    const float4 a1 = *(const float4*)(arow1 + (fq << 2));
#pragma unroll
    for (int c = 0; c < 4; ++c) {
      const float4 b = *(const float4*)(sh_b + ((fq << 2) + c) * SB + j0);  // lane-consecutive b128
      const float a0c = (c == 0) ? a0.x : (c == 1) ? a0.y : (c == 2) ? a0.z : a0.w;
      const float a1c = (c == 0) ? a1.x : (c == 1) ? a1.y : (c == 2) ? a1.z : a1.w;
      float d;
      d = a0c - b.x; acc00 = fmaf(d, d, acc00);
      d = a0c - b.y; acc01 = fmaf(d, d, acc01);
      d = a0c - b.z; acc02 = fmaf(d, d, acc02);
      d = a0c - b.w; acc03 = fmaf(d, d, acc03);
      d = a1c - b.x; acc10 = fmaf(d, d, acc10);
      d = a1c - b.y; acc11 = fmaf(d, d, acc11);
      d = a1c - b.z; acc12 = fmaf(d, d, acc12);
      d = a1c - b.w; acc13 = fmaf(d, d, acc13);
    }
  }

  // kernel_value = exp(-ds / (2 sigma^2)); softmax over j for BOTH rows.
  // Row = 32 lanes x 4 regs; xor offsets <32 stay within each 32-lane half.
  const float k00 = __expf(acc00 * cneg);
  const float k01 = __expf(acc01 * cneg);
  const float k02 = __expf(acc02 * cneg);
  const float k03 = __expf(acc03 * cneg);
  const float k10 = __expf(acc10 * cneg);
  const float k11 = __expf(acc11 * cneg);
  const float k12 = __expf(acc12 * cneg);
  const float k13 = __expf(acc13 * cneg);

  float mx0 = fmaxf(fmaxf(k00, k01), fmaxf(k02, k03));
  float mx1 = fmaxf(fmaxf(k10, k11), fmaxf(k12, k13));
#pragma unroll
  for (int off = 16; off >= 1; off >>= 1) {
    mx0 = fmaxf(mx0, __shfl_xor(mx0, off, 64));
    mx1 = fmaxf(mx1, __shfl_xor(mx1, off, 64));
  }
  const float e00 = __expf(k00 - mx0);
  const float e01 = __expf(k01 - mx0);
  const float e02 = __expf(k02 - mx0);
  const float e03 = __expf(k03 - mx0);
  const float e10 = __expf(k10 - mx1);
  const float e11 = __expf(k11 - mx1);
  const float e12 = __expf(k12 - mx1);
  const float e13 = __expf(k13 - mx1);
  float s0 = e00 + e01 + e02 + e03;
  float s1 = e10 + e11 + e12 + e13;
#pragma unroll
  for (int off = 16; off >= 1; off >>= 1) {
    s0 += __shfl_xor(s0, off, 64);
    s1 += __shfl_xor(s1, off, 64);
  }
  const float r0 = 1.0f / s0;
  const float r1 = 1.0f / s1;

  *(float4*)(out + (size_t)(n * RR + i0 + ty) * RR + j0) =
      make_float4(e00 * r0, e01 * r0, e02 * r0, e03 * r0);
  *(float4*)(out + (size_t)(n * RR + i0 + ty + 8) * RR + j0) =
      make_float4(e10 * r1, e11 * r1, e12 * r1, e13 * r1);
}

extern "C" void kernel_launch(void* const* d_in, const int* in_sizes, int n_in,
                              void* d_out, int out_size, void* d_ws, size_t ws_size,
                              hipStream_t stream) {
  const float* x1 = (const float*)d_in[0];
  const float* x2 = (const float*)d_in[1];
  const float* sigma = (const float*)d_in[2];
  const float* mean = (const float*)d_in[3];
  float* out = (float*)d_out;
  (void)d_ws; (void)ws_size;  // deliberately unused: keep the 268 MB ws poison off our path

  gauss_fused<<<dim3(NB * 8), dim3(256), 0, stream>>>(x1, x2, sigma, mean, out);
}

// Round 3
// 65.390 us; speedup vs baseline: 2.2279x; 1.0494x over previous
//
#include <hip/hip_runtime.h>

#define NB 32
#define RR 128
#define FF 128
#define SB 132  // LDS row stride for transposed b: 132*4B = 528B, 16B-aligned rows,
                // 4-way write conflict (~1.58x) on staging, conflict-free b128 reads

// v4: v3 + XCD-chunked swizzle + clustered staging loads.
// v3 post-mortem: v1 (8 barriers, 2x LDS reads) and v3 (1 barrier) within 0.8 us
// -> compute/LDS/barriers are NOT the bottleneck. Residual ~13 us attributed to
// the post-fill cold staging phase: the 268 MB ws poison fill evicts all of L3
// every iteration, and the 8 blocks sharing one x2[n] slice are round-robined
// onto 8 DIFFERENT XCDs (private L2s) -> 8x redundant cold fetches.
// Fix (T1): remap blockIdx so XCD x = bid&7 owns n in [4x, 4x+4) -- all 8
// i-tiles of an n land on ONE XCD; its L2 fetches the 64 KB slice once.
// Also: issue all 18 staging float4 global loads before any LDS write (MLP
// under post-fill HBM latency), then drain to LDS. 18 float4 ~ 72 VGPR live,
// no arrays with runtime indices (rule #20) -> no spills.
// Still no d_ws use: the 268 MB harness poison fill stays the only big HBM user.
__global__ __launch_bounds__(256) void gauss_fused(const float* __restrict__ x1,
                                                   const float* __restrict__ x2,
                                                   const float* __restrict__ sigma,
                                                   const float* __restrict__ mean,
                                                   float* __restrict__ out) {
  __shared__ __align__(16) float sh_b[FF * SB];   // 67584 B, transposed [f][j]
  __shared__ __align__(16) float sh_a[16 * FF];   // 8192 B, 16 x1 rows, mean folded

  // XCD-chunked mapping: dispatch d -> XCD d&7 (round-robin, 8 XCDs).
  // XCD x serves n = 4x .. 4x+3, 8 i-tiles each (grid 256 = 8 XCDs x 4 n x 8 tiles).
  const int d = blockIdx.x;
  const int xcd = d & 7;
  const int k = d >> 3;                  // 0..31 within-XCD slot
  const int n = (xcd << 2) + (k >> 3);   // 4 consecutive n per XCD
  const int i0 = (k & 7) << 4;           // 16 rows per block
  const int tid = threadIdx.x;
  const int tx = tid & 31;   // j-quad
  const int ty = tid >> 5;   // 0..7 -> rows i0+ty and i0+ty+8

  const float mval = mean[0];
  const float sg = sigma[0];
  const float cneg = -1.0f / (2.0f * sg * sg);

  const float* __restrict__ x2base = x2 + (size_t)n * RR * FF;
  const int jj = tid >> 3;        // 0..31: j within each 32-row chunk
  const int fo = (tid & 7) << 2;  // 0,4,...,28: f-quad within each 32-f chunk

  // ---- staging: cluster ALL global loads first (18 float4 in flight) ----
  float4 q0, q1, q2, q3, q4, q5, q6, q7, q8, q9, q10, q11, q12, q13, q14, q15;
#define LDQ(fc, p) *(const float4*)(x2base + (size_t)(jj + ((p) << 5)) * FF + ((fc) << 5) + fo)
  q0 = LDQ(0, 0);  q1 = LDQ(0, 1);  q2 = LDQ(0, 2);  q3 = LDQ(0, 3);
  q4 = LDQ(1, 0);  q5 = LDQ(1, 1);  q6 = LDQ(1, 2);  q7 = LDQ(1, 3);
  q8 = LDQ(2, 0);  q9 = LDQ(2, 1);  q10 = LDQ(2, 2); q11 = LDQ(2, 3);
  q12 = LDQ(3, 0); q13 = LDQ(3, 1); q14 = LDQ(3, 2); q15 = LDQ(3, 3);
#undef LDQ
  const float4* asrc = (const float4*)(x1 + (size_t)(n * RR + i0) * FF);
  const float4 v0 = asrc[tid];
  const float4 v1 = asrc[tid + 256];

  // ---- drain to LDS ----
  ((float4*)sh_a)[tid] = make_float4(v0.x - mval, v0.y - mval, v0.z - mval, v0.w - mval);
  ((float4*)sh_a)[tid + 256] = make_float4(v1.x - mval, v1.y - mval, v1.z - mval, v1.w - mval);
#define STW(q, fc, p)                                    \
  {                                                      \
    const int f0 = ((fc) << 5) + fo;                     \
    const int j = jj + ((p) << 5);                       \
    sh_b[(f0 + 0) * SB + j] = (q).x;                     \
    sh_b[(f0 + 1) * SB + j] = (q).y;                     \
    sh_b[(f0 + 2) * SB + j] = (q).z;                     \
    sh_b[(f0 + 3) * SB + j] = (q).w;                     \
  }
  STW(q0, 0, 0)  STW(q1, 0, 1)  STW(q2, 0, 2)  STW(q3, 0, 3)
  STW(q4, 1, 0)  STW(q5, 1, 1)  STW(q6, 1, 2)  STW(q7, 1, 3)
  STW(q8, 2, 0)  STW(q9, 2, 1)  STW(q10, 2, 2) STW(q11, 2, 3)
  STW(q12, 3, 0) STW(q13, 3, 1) STW(q14, 3, 2) STW(q15, 3, 3)
#undef STW
  __syncthreads();  // the ONLY barrier

  float acc00 = 0.f, acc01 = 0.f, acc02 = 0.f, acc03 = 0.f;
  float acc10 = 0.f, acc11 = 0.f, acc12 = 0.f, acc13 = 0.f;
  const int j0 = tx << 2;
  const float* __restrict__ arow0 = sh_a + ty * FF;
  const float* __restrict__ arow1 = sh_a + (ty + 8) * FF;

#pragma unroll 4
  for (int fq = 0; fq < 32; ++fq) {
    const float4 a0 = *(const float4*)(arow0 + (fq << 2));  // broadcast b128
    const float4 a1 = *(const float4*)(arow1 + (fq << 2));
#pragma unroll
    for (int c = 0; c < 4; ++c) {
      const float4 b = *(const float4*)(sh_b + ((fq << 2) + c) * SB + j0);  // lane-consecutive b128
      const float a0c = (c == 0) ? a0.x : (c == 1) ? a0.y : (c == 2) ? a0.z : a0.w;
      const float a1c = (c == 0) ? a1.x : (c == 1) ? a1.y : (c == 2) ? a1.z : a1.w;
      float d;
      d = a0c - b.x; acc00 = fmaf(d, d, acc00);
      d = a0c - b.y; acc01 = fmaf(d, d, acc01);
      d = a0c - b.z; acc02 = fmaf(d, d, acc02);
      d = a0c - b.w; acc03 = fmaf(d, d, acc03);
      d = a1c - b.x; acc10 = fmaf(d, d, acc10);
      d = a1c - b.y; acc11 = fmaf(d, d, acc11);
      d = a1c - b.z; acc12 = fmaf(d, d, acc12);
      d = a1c - b.w; acc13 = fmaf(d, d, acc13);
    }
  }

  // kernel_value = exp(-ds / (2 sigma^2)); softmax over j for BOTH rows.
  // Row = 32 lanes x 4 regs; xor offsets <32 stay within each 32-lane half.
  const float k00 = __expf(acc00 * cneg);
  const float k01 = __expf(acc01 * cneg);
  const float k02 = __expf(acc02 * cneg);
  const float k03 = __expf(acc03 * cneg);
  const float k10 = __expf(acc10 * cneg);
  const float k11 = __expf(acc11 * cneg);
  const float k12 = __expf(acc12 * cneg);
  const float k13 = __expf(acc13 * cneg);

  float mx0 = fmaxf(fmaxf(k00, k01), fmaxf(k02, k03));
  float mx1 = fmaxf(fmaxf(k10, k11), fmaxf(k12, k13));
#pragma unroll
  for (int off = 16; off >= 1; off >>= 1) {
    mx0 = fmaxf(mx0, __shfl_xor(mx0, off, 64));
    mx1 = fmaxf(mx1, __shfl_xor(mx1, off, 64));
  }
  const float e00 = __expf(k00 - mx0);
  const float e01 = __expf(k01 - mx0);
  const float e02 = __expf(k02 - mx0);
  const float e03 = __expf(k03 - mx0);
  const float e10 = __expf(k10 - mx1);
  const float e11 = __expf(k11 - mx1);
  const float e12 = __expf(k12 - mx1);
  const float e13 = __expf(k13 - mx1);
  float s0 = e00 + e01 + e02 + e03;
  float s1 = e10 + e11 + e12 + e13;
#pragma unroll
  for (int off = 16; off >= 1; off >>= 1) {
    s0 += __shfl_xor(s0, off, 64);
    s1 += __shfl_xor(s1, off, 64);
  }
  const float r0 = 1.0f / s0;
  const float r1 = 1.0f / s1;

  *(float4*)(out + (size_t)(n * RR + i0 + ty) * RR + j0) =
      make_float4(e00 * r0, e01 * r0, e02 * r0, e03 * r0);
  *(float4*)(out + (size_t)(n * RR + i0 + ty + 8) * RR + j0) =
      make_float4(e10 * r1, e11 * r1, e12 * r1, e13 * r1);
}

extern "C" void kernel_launch(void* const* d_in, const int* in_sizes, int n_in,
                              void* d_out, int out_size, void* d_ws, size_t ws_size,
                              hipStream_t stream) {
  const float* x1 = (const float*)d_in[0];
  const float* x2 = (const float*)d_in[1];
  const float* sigma = (const float*)d_in[2];
  const float* mean = (const float*)d_in[3];
  float* out = (float*)d_out;
  (void)d_ws; (void)ws_size;  // deliberately unused: keep the 268 MB ws poison off our path

  gauss_fused<<<dim3(NB * 8), dim3(256), 0, stream>>>(x1, x2, sigma, mean, out);
}